// Round 13
// baseline (575.348 us; speedup 1.0000x reference)
//
#include <hip/hip_runtime.h>
#include <cstddef>
#include <cstdint>

#define NN 50000
#define NE 800000

typedef __bf16 bf16x8 __attribute__((ext_vector_type(8)));
typedef float  f32x4  __attribute__((ext_vector_type(4)));

__device__ __forceinline__ bf16x8 ldfrag(const __bf16* __restrict__ wfr, int f, int lane) {
    return *reinterpret_cast<const bf16x8*>(wfr + (size_t)(f * 64 + lane) * 8);
}
__device__ __forceinline__ f32x4 mfma16(bf16x8 a, bf16x8 b, f32x4 c) {
    return __builtin_amdgcn_mfma_f32_16x16x32_bf16(a, b, c, 0, 0, 0);
}
__device__ __forceinline__ bool idx_is64(const int* eidx) {
    return ((eidx[1] | eidx[3] | eidx[5] | eidx[7]) == 0);
}
__device__ __forceinline__ int ld_src(const int* eidx, bool is64, int e) {
    return is64 ? eidx[(size_t)2 * e] : eidx[e];
}
__device__ __forceinline__ int ld_dst(const int* eidx, bool is64, int e) {
    return is64 ? eidx[2 * ((size_t)NE + e)] : eidx[(size_t)NE + e];
}
__device__ __forceinline__ bf16x8 cvt8(const float* __restrict__ p) {
    float4 v0 = *reinterpret_cast<const float4*>(p);
    float4 v1 = *reinterpret_cast<const float4*>(p + 4);
    bf16x8 r;
    r[0] = (__bf16)v0.x; r[1] = (__bf16)v0.y; r[2] = (__bf16)v0.z; r[3] = (__bf16)v0.w;
    r[4] = (__bf16)v1.x; r[5] = (__bf16)v1.y; r[6] = (__bf16)v1.z; r[7] = (__bf16)v1.w;
    return r;
}

// ---------------- weight prep: f32 [K][64] -> bf16 B-fragment layout ----------------
// frag(kt,nt): lane holds B[k = kt*32 + (lane>>4)*8 + b][n = nt*16 + (lane&15)], b=0..7
// table: W_le f0..7, W1 f8..15, W2 f16..23, We1 f24..47, We2 f48..55, We3 f56..63
__global__ __launch_bounds__(256) void prep(const float* __restrict__ wle, const float* __restrict__ w1,
                                            const float* __restrict__ w2, const float* __restrict__ we1,
                                            const float* __restrict__ we2, const float* __restrict__ we3,
                                            __bf16* __restrict__ wfr) {
    int sid = blockIdx.x * 256 + threadIdx.x;
    int f = sid >> 6, lane = sid & 63;
    const float* W; int fo;
    if (f < 8)       { W = wle; fo = 0; }
    else if (f < 16) { W = w1;  fo = 8; }
    else if (f < 24) { W = w2;  fo = 16; }
    else if (f < 48) { W = we1; fo = 24; }
    else if (f < 56) { W = we2; fo = 48; }
    else             { W = we3; fo = 56; }
    int lf = f - fo, kt = lf >> 2, nt = lf & 3;
    int g = lane >> 4, c = lane & 15;
#pragma unroll
    for (int b = 0; b < 8; b++) {
        int k = kt * 32 + g * 8 + b;
        int n = nt * 16 + c;
        wfr[(size_t)(f * 64 + lane) * 8 + b] = (__bf16)W[(size_t)k * 64 + n];
    }
}

// ---------------- CSR build: degree count -> scan -> slot fill (edge -> sorted position) ----------------
__global__ __launch_bounds__(256) void kdeg(const int* __restrict__ eidx, int* __restrict__ cnt) {
    const bool is64 = idx_is64(eidx);
    int e = blockIdx.x * 256 + threadIdx.x;
    atomicAdd(&cnt[ld_dst(eidx, is64, e)], 1);
}

__global__ __launch_bounds__(1024) void kscan(const int* __restrict__ cnt, int* __restrict__ rowptr) {
    __shared__ int ps[1024];
    const int t = threadIdx.x;
    const int CH = (NN + 1023) / 1024;  // 49
    const int b0 = t * CH;
    int s = 0;
    for (int i = 0; i < CH; i++) { int n = b0 + i; if (n < NN) s += cnt[n]; }
    ps[t] = s;
    __syncthreads();
    for (int off = 1; off < 1024; off <<= 1) {
        int v = (t >= off) ? ps[t - off] : 0;
        __syncthreads();
        ps[t] += v;
        __syncthreads();
    }
    int run = (t == 0) ? 0 : ps[t - 1];
    for (int i = 0; i < CH; i++) {
        int n = b0 + i;
        if (n < NN) { rowptr[n] = run; run += cnt[n]; }
    }
    if (t == 1023) rowptr[NN] = ps[1023];
}

__global__ __launch_bounds__(256) void kfill(const int* __restrict__ eidx, int* __restrict__ cnt2,
                                             const int* __restrict__ rowptr, int* __restrict__ perm) {
    const bool is64 = idx_is64(eidx);
    int e = blockIdx.x * 256 + threadIdx.x;
    int dn = ld_dst(eidx, is64, e);
    int slot = rowptr[dn] + atomicAdd(&cnt2[dn], 1);
    perm[e] = slot;   // edge e's row goes to sorted position slot
}

// ---------------- k1m: msg = relu(em[src] + ef@W_le + b_le); sequential compute, dst-sorted write ----------------
__global__ __launch_bounds__(256) void k1m(const float* __restrict__ em, const int* __restrict__ eidx,
                                           const float* __restrict__ ef, const __bf16* __restrict__ wfr,
                                           const float* __restrict__ ble, const int* __restrict__ perm,
                                           __bf16* __restrict__ msg) {
    __shared__ __bf16 Msh[4][16][72];
    const int t = threadIdx.x;
    const int base = blockIdx.x * 64;
    const int lane = t & 63, w = t >> 6, c = lane & 15, g = lane >> 4;
    const int erow = base + w * 16 + c;
    const bool is64 = idx_is64(eidx);
    bf16x8 a[2];
#pragma unroll
    for (int kt = 0; kt < 2; kt++)
        a[kt] = cvt8(ef + (size_t)erow * 64 + kt * 32 + g * 8);
    f32x4 acc[4] = {{0.f,0.f,0.f,0.f},{0.f,0.f,0.f,0.f},{0.f,0.f,0.f,0.f},{0.f,0.f,0.f,0.f}};
#pragma unroll
    for (int kt = 0; kt < 2; kt++)
#pragma unroll
        for (int nt = 0; nt < 4; nt++) acc[nt] = mfma16(a[kt], ldfrag(wfr, kt * 4 + nt, lane), acc[nt]);
#pragma unroll
    for (int rr = 0; rr < 4; rr++) {
        int e = base + w * 16 + g * 4 + rr;
        int sn = ld_src(eidx, is64, e);
#pragma unroll
        for (int nt = 0; nt < 4; nt++) {
            int col = nt * 16 + c;
            float v = acc[nt][rr] + ble[col] + em[(size_t)sn * 64 + col];
            Msh[w][g * 4 + rr][col] = (__bf16)(v > 0.f ? v : 0.f);  // wave-private slab
        }
    }
    // store: 8 lanes cover one 128B row; destination row = perm[edge] (dst-sorted position)
#pragma unroll
    for (int p = 0; p < 2; p++) {
        int r16 = p * 8 + (lane >> 3);
        int e = base + w * 16 + r16;
        size_t drow = (size_t)perm[e];
        bf16x8 mv = *reinterpret_cast<const bf16x8*>(&Msh[w][r16][(lane & 7) * 8]);
        *reinterpret_cast<bf16x8*>(msg + drow * 64 + (lane & 7) * 8) = mv;
    }
}

// ---------------- k1g: aggr[n] = sum over contiguous sorted run [rowptr[n], rowptr[n+1]) ----------------
__global__ __launch_bounds__(256) void k1g(const int* __restrict__ rowptr, const __bf16* __restrict__ msg,
                                           float* __restrict__ nodebuf) {
    const int t = threadIdx.x, lane = t & 63, w = t >> 6;
    const int n = blockIdx.x * 4 + w;
    const int s0 = rowptr[n], s1 = rowptr[n + 1];
    const int q = lane >> 3, r = lane & 7;
    float acc[8] = {0.f,0.f,0.f,0.f,0.f,0.f,0.f,0.f};
    for (int j = s0; j < s1; j += 8) {
        int jj = j + q;
        if (jj < s1) {
            bf16x8 m = *reinterpret_cast<const bf16x8*>(msg + (size_t)jj * 64 + r * 8);
#pragma unroll
            for (int i = 0; i < 8; i++) acc[i] += (float)m[i];
        }
    }
#pragma unroll
    for (int mask = 8; mask <= 32; mask <<= 1)
#pragma unroll
        for (int i = 0; i < 8; i++) acc[i] += __shfl_xor(acc[i], mask);
    if (lane < 8) {
        *reinterpret_cast<float4*>(nodebuf + (size_t)n * 64 + lane * 8)     = make_float4(acc[0], acc[1], acc[2], acc[3]);
        *reinterpret_cast<float4*>(nodebuf + (size_t)n * 64 + lane * 8 + 4) = make_float4(acc[4], acc[5], acc[6], acc[7]);
    }
}

// ---------------- k2: h = em + aggr; h2 = relu(h@W1+b1)@W2+b2 (in-place); BN partial sums ----------------
__global__ __launch_bounds__(256) void k2(const float* __restrict__ em, float* __restrict__ nb,
                                          const __bf16* __restrict__ wfr, const float* __restrict__ b1,
                                          const float* __restrict__ b2, float* __restrict__ sums) {
    __shared__ __bf16 Ysh[64][72];
    __shared__ float bs[128];
    const int t = threadIdx.x;
    const int base = blockIdx.x * 64;
    if (t < 128) bs[t] = 0.f;
    __syncthreads();
    const int lane = t & 63, w = t >> 6, c = lane & 15, g = lane >> 4;
    const int arow = base + w * 16 + c;
    const size_t rl = (size_t)(arow < NN ? arow : NN - 1) * 64;
    bf16x8 a[2];
#pragma unroll
    for (int kt = 0; kt < 2; kt++) {
        int off = kt * 32 + g * 8;
        float4 e0 = *reinterpret_cast<const float4*>(em + rl + off);
        float4 e1 = *reinterpret_cast<const float4*>(em + rl + off + 4);
        float4 n0 = *reinterpret_cast<const float4*>(nb + rl + off);
        float4 n1 = *reinterpret_cast<const float4*>(nb + rl + off + 4);
        bf16x8 r;
        r[0] = (__bf16)(e0.x + n0.x); r[1] = (__bf16)(e0.y + n0.y);
        r[2] = (__bf16)(e0.z + n0.z); r[3] = (__bf16)(e0.w + n0.w);
        r[4] = (__bf16)(e1.x + n1.x); r[5] = (__bf16)(e1.y + n1.y);
        r[6] = (__bf16)(e1.z + n1.z); r[7] = (__bf16)(e1.w + n1.w);
        a[kt] = r;
    }
    f32x4 a1[4] = {{0.f,0.f,0.f,0.f},{0.f,0.f,0.f,0.f},{0.f,0.f,0.f,0.f},{0.f,0.f,0.f,0.f}};
#pragma unroll
    for (int kt = 0; kt < 2; kt++)
#pragma unroll
        for (int nt = 0; nt < 4; nt++) a1[nt] = mfma16(a[kt], ldfrag(wfr, 8 + kt * 4 + nt, lane), a1[nt]);
#pragma unroll
    for (int nt = 0; nt < 4; nt++) {
        float bb = b1[nt * 16 + c];
#pragma unroll
        for (int rr = 0; rr < 4; rr++) {
            float v = a1[nt][rr] + bb;
            v = v > 0.f ? v : 0.f;
            Ysh[w * 16 + g * 4 + rr][nt * 16 + c] = (__bf16)v;  // wave-private slab
        }
    }
    bf16x8 ya[2];
#pragma unroll
    for (int kt = 0; kt < 2; kt++)
        ya[kt] = *reinterpret_cast<const bf16x8*>(&Ysh[w * 16 + c][kt * 32 + g * 8]);
    f32x4 a2[4] = {{0.f,0.f,0.f,0.f},{0.f,0.f,0.f,0.f},{0.f,0.f,0.f,0.f},{0.f,0.f,0.f,0.f}};
#pragma unroll
    for (int kt = 0; kt < 2; kt++)
#pragma unroll
        for (int nt = 0; nt < 4; nt++) a2[nt] = mfma16(ya[kt], ldfrag(wfr, 16 + kt * 4 + nt, lane), a2[nt]);
#pragma unroll
    for (int nt = 0; nt < 4; nt++) {
        int col = nt * 16 + c;
        float bb = b2[col];
        float ss = 0.f, qq = 0.f;
#pragma unroll
        for (int rr = 0; rr < 4; rr++) {
            int row = base + w * 16 + g * 4 + rr;
            if (row < NN) {
                float v = a2[nt][rr] + bb;
                nb[(size_t)row * 64 + col] = v;
                ss += v; qq += v * v;
            }
        }
        ss += __shfl_xor(ss, 16); ss += __shfl_xor(ss, 32);
        qq += __shfl_xor(qq, 16); qq += __shfl_xor(qq, 32);
        if (g == 0) { atomicAdd(&bs[col], ss); atomicAdd(&bs[64 + col], qq); }
    }
    __syncthreads();
    if (t < 128) atomicAdd(&sums[t], bs[t]);
}

// ---------------- k3: x = relu(BN(h2)) in-place; also bf16 copy for gathers ----------------
__global__ __launch_bounds__(256) void k3(float* __restrict__ nb, const float* __restrict__ sums,
                                          const float* __restrict__ gx, const float* __restrict__ bx,
                                          __bf16* __restrict__ wsx) {
    size_t i4 = (size_t)(blockIdx.x * 256 + threadIdx.x) * 4;
    int col0 = (int)(i4 & 63);
    float4 v = *reinterpret_cast<const float4*>(nb + i4);
    const float* pv = reinterpret_cast<const float*>(&v);
    float o[4]; short so[4];
#pragma unroll
    for (int j = 0; j < 4; j++) {
        int col = col0 + j;
        float m   = sums[col] * (1.0f / 50000.0f);
        float var = sums[64 + col] * (1.0f / 50000.0f) - m * m;
        float inv = rsqrtf(var + 1e-5f);
        float x = (pv[j] - m) * inv * gx[col] + bx[col];
        x = x > 0.f ? x : 0.f;
        o[j] = x;
        so[j] = __builtin_bit_cast(short, (__bf16)x);
    }
    *reinterpret_cast<float4*>(nb + i4) = make_float4(o[0], o[1], o[2], o[3]);
    *reinterpret_cast<short4*>(wsx + i4) = make_short4(so[0], so[1], so[2], so[3]);
}

// ---------------- k4: fused 3-layer edge MLP, TWO 64-edge tiles per block (latency-hiding ILP) ----------------
__global__ __launch_bounds__(256) void k4(const int* __restrict__ eidx, const float* __restrict__ ef,
                                          const __bf16* __restrict__ wsx, const __bf16* __restrict__ wfr,
                                          const float* __restrict__ be1, const float* __restrict__ be2,
                                          const float* __restrict__ be3, float* __restrict__ eout,
                                          float* __restrict__ pws) {
    __shared__ __bf16 Ysh[2][64][72];
    __shared__ float bs[128];
    const int t = threadIdx.x;
    const int blockb = blockIdx.x * 128;
    if (t < 128) bs[t] = 0.f;
    __syncthreads();
    const int lane = t & 63, w = t >> 6, c = lane & 15, g = lane >> 4;
    const bool is64 = idx_is64(eidx);

    int erow[2], sn[2], dn[2];
    bf16x8 xs[2][2], xd[2][2], ea[2][2];
#pragma unroll
    for (int tt = 0; tt < 2; tt++) {
        erow[tt] = blockb + tt * 64 + w * 16 + c;
        sn[tt] = ld_src(eidx, is64, erow[tt]);
        dn[tt] = ld_dst(eidx, is64, erow[tt]);
#pragma unroll
        for (int kt = 0; kt < 2; kt++) {
            int off = kt * 32 + g * 8;
            xs[tt][kt] = *reinterpret_cast<const bf16x8*>(wsx + (size_t)sn[tt] * 64 + off);
            xd[tt][kt] = *reinterpret_cast<const bf16x8*>(wsx + (size_t)dn[tt] * 64 + off);
            ea[tt][kt] = cvt8(ef + (size_t)erow[tt] * 64 + off);
        }
    }
    f32x4 a1[2][4];
#pragma unroll
    for (int tt = 0; tt < 2; tt++)
#pragma unroll
        for (int nt = 0; nt < 4; nt++) a1[tt][nt] = f32x4{0.f,0.f,0.f,0.f};
#pragma unroll
    for (int tt = 0; tt < 2; tt++)
#pragma unroll
        for (int kt = 0; kt < 2; kt++)
#pragma unroll
            for (int nt = 0; nt < 4; nt++) a1[tt][nt] = mfma16(xs[tt][kt], ldfrag(wfr, 24 + kt * 4 + nt, lane), a1[tt][nt]);
#pragma unroll
    for (int tt = 0; tt < 2; tt++)
#pragma unroll
        for (int kt = 0; kt < 2; kt++)
#pragma unroll
            for (int nt = 0; nt < 4; nt++) a1[tt][nt] = mfma16(xd[tt][kt], ldfrag(wfr, 32 + kt * 4 + nt, lane), a1[tt][nt]);
#pragma unroll
    for (int tt = 0; tt < 2; tt++)
#pragma unroll
        for (int kt = 0; kt < 2; kt++)
#pragma unroll
            for (int nt = 0; nt < 4; nt++) a1[tt][nt] = mfma16(ea[tt][kt], ldfrag(wfr, 40 + kt * 4 + nt, lane), a1[tt][nt]);
#pragma unroll
    for (int tt = 0; tt < 2; tt++)
#pragma unroll
        for (int nt = 0; nt < 4; nt++) {
            float bb = be1[nt * 16 + c];
#pragma unroll
            for (int rr = 0; rr < 4; rr++) {
                float v = a1[tt][nt][rr] + bb;
                v = v > 0.f ? v : 0.f;
                Ysh[tt][w * 16 + g * 4 + rr][nt * 16 + c] = (__bf16)v;  // wave-private slab
            }
        }
    bf16x8 ya[2][2];
#pragma unroll
    for (int tt = 0; tt < 2; tt++)
#pragma unroll
        for (int kt = 0; kt < 2; kt++)
            ya[tt][kt] = *reinterpret_cast<const bf16x8*>(&Ysh[tt][w * 16 + c][kt * 32 + g * 8]);
    f32x4 a2[2][4];
#pragma unroll
    for (int tt = 0; tt < 2; tt++)
#pragma unroll
        for (int nt = 0; nt < 4; nt++) a2[tt][nt] = f32x4{0.f,0.f,0.f,0.f};
#pragma unroll
    for (int tt = 0; tt < 2; tt++)
#pragma unroll
        for (int kt = 0; kt < 2; kt++)
#pragma unroll
            for (int nt = 0; nt < 4; nt++) a2[tt][nt] = mfma16(ya[tt][kt], ldfrag(wfr, 48 + kt * 4 + nt, lane), a2[tt][nt]);
#pragma unroll
    for (int tt = 0; tt < 2; tt++)
#pragma unroll
        for (int nt = 0; nt < 4; nt++) {
            float bb = be2[nt * 16 + c];
#pragma unroll
            for (int rr = 0; rr < 4; rr++) {
                float v = a2[tt][nt][rr] + bb;
                v = v > 0.f ? v : 0.f;
                Ysh[tt][w * 16 + g * 4 + rr][nt * 16 + c] = (__bf16)v;  // overwrite own slab
            }
        }
#pragma unroll
    for (int tt = 0; tt < 2; tt++)
#pragma unroll
        for (int kt = 0; kt < 2; kt++)
            ya[tt][kt] = *reinterpret_cast<const bf16x8*>(&Ysh[tt][w * 16 + c][kt * 32 + g * 8]);
    f32x4 a3[2][4];
#pragma unroll
    for (int tt = 0; tt < 2; tt++)
#pragma unroll
        for (int nt = 0; nt < 4; nt++) a3[tt][nt] = f32x4{0.f,0.f,0.f,0.f};
#pragma unroll
    for (int tt = 0; tt < 2; tt++)
#pragma unroll
        for (int kt = 0; kt < 2; kt++)
#pragma unroll
            for (int nt = 0; nt < 4; nt++) a3[tt][nt] = mfma16(ya[tt][kt], ldfrag(wfr, 56 + kt * 4 + nt, lane), a3[tt][nt]);
#pragma unroll
    for (int tt = 0; tt < 2; tt++)
#pragma unroll
        for (int nt = 0; nt < 4; nt++) {
            int col = nt * 16 + c;
            float bb = be3[col];
            float ss = 0.f, qq = 0.f;
#pragma unroll
            for (int rr = 0; rr < 4; rr++) {
                int e = blockb + tt * 64 + w * 16 + g * 4 + rr;
                float v = a3[tt][nt][rr] + bb;
                eout[(size_t)e * 64 + col] = v;
                ss += v; qq += v * v;
            }
            ss += __shfl_xor(ss, 16); ss += __shfl_xor(ss, 32);
            qq += __shfl_xor(qq, 16); qq += __shfl_xor(qq, 32);
            if (g == 0) { atomicAdd(&bs[col], ss); atomicAdd(&bs[64 + col], qq); }
        }
    __syncthreads();
    if (t < 128) pws[(size_t)t * (NE / 128) + blockIdx.x] = bs[t];
}

// ---------------- k4r: reduce per-block partials -> edge BN sums ----------------
__global__ __launch_bounds__(256) void k4r(const float* __restrict__ pws, float* __restrict__ sums) {
    int b = blockIdx.x;
    float s = 0.f;
    for (int i = threadIdx.x; i < NE / 128; i += 256) s += pws[(size_t)b * (NE / 128) + i];
#pragma unroll
    for (int m = 32; m >= 1; m >>= 1) s += __shfl_xor(s, m);
    __shared__ float acc4[4];
    int lane = threadIdx.x & 63, wid = threadIdx.x >> 6;
    if (lane == 0) acc4[wid] = s;
    __syncthreads();
    if (threadIdx.x == 0) sums[128 + b] = acc4[0] + acc4[1] + acc4[2] + acc4[3];
}

// ---------------- k5: edge_out = relu(BN(e3)) in-place ----------------
__global__ __launch_bounds__(256) void k5(float* __restrict__ eo, const float* __restrict__ sums,
                                          const float* __restrict__ ge, const float* __restrict__ be) {
    size_t i4 = (size_t)(blockIdx.x * 256 + threadIdx.x) * 4;
    int col0 = (int)(i4 & 63);
    float4 v = *reinterpret_cast<const float4*>(eo + i4);
    const float* pv = reinterpret_cast<const float*>(&v);
    float o[4];
#pragma unroll
    for (int j = 0; j < 4; j++) {
        int col = col0 + j;
        float m   = sums[128 + col] * (1.0f / 800000.0f);
        float var = sums[192 + col] * (1.0f / 800000.0f) - m * m;
        float inv = rsqrtf(var + 1e-5f);
        float x = (pv[j] - m) * inv * ge[col] + be[col];
        o[j] = x > 0.f ? x : 0.f;
    }
    *reinterpret_cast<float4*>(eo + i4) = make_float4(o[0], o[1], o[2], o[3]);
}

extern "C" void kernel_launch(void* const* d_in, const int* in_sizes, int n_in,
                              void* d_out, int out_size, void* d_ws, size_t ws_size,
                              hipStream_t stream) {
    const float* em   = (const float*)d_in[0];
    const int*   eidx = (const int*)d_in[1];
    const float* ef   = (const float*)d_in[2];
    const float* b_le = (const float*)d_in[4];
    const float* b1   = (const float*)d_in[6];
    const float* b2   = (const float*)d_in[8];
    const float* gx   = (const float*)d_in[9];
    const float* bx   = (const float*)d_in[10];
    const float* be1  = (const float*)d_in[12];
    const float* be2  = (const float*)d_in[14];
    const float* be3  = (const float*)d_in[16];
    const float* ge   = (const float*)d_in[17];
    const float* be   = (const float*)d_in[18];

    float* out = (float*)d_out;
    float* nodebuf = out;                          // 50000*64 f32 (aggr -> h2 -> x_em in place)
    float* eout = out + (size_t)NN * 64;           // 800000*64 f32 (e3 -> edge_out in place)

    // ws layout (bytes):
    // sums 1KB | wfr 64KB | wsx 6.4MB | csr { cnt 200K, cnt2 200K, rowptr 200K, perm 3.2MB } | msg 102.4MB
    // pws (3.2MB, used by k4/k4r) ALIASES the csr region — disjoint lifetimes (csr dead after k1g).
    char* wsb = (char*)d_ws;
    float*  sums   = (float*)wsb;
    __bf16* wfr    = (__bf16*)(wsb + 1024);
    __bf16* wsx    = (__bf16*)(wsb + 1024 + 65536);
    size_t  off    = 1024 + 65536 + (size_t)NN * 64 * 2;   // 6,466,560
    char*   csrb   = wsb + off;
    int*    cnt    = (int*)(csrb);
    int*    cnt2   = (int*)(csrb + 200192);
    int*    rowptr = (int*)(csrb + 2 * 200192);
    int*    perm   = (int*)(csrb + 3 * 200192);
    float*  pws    = (float*)csrb;                          // alias: k4 phase only
    __bf16* msg    = (__bf16*)(csrb + 3 * 200192 + (size_t)NE * 4);

    hipMemsetAsync(sums, 0, 256 * sizeof(float), stream);
    hipMemsetAsync(cnt, 0, 200192 * 2, stream);    // cnt + cnt2

    prep<<<16, 256, 0, stream>>>((const float*)d_in[3], (const float*)d_in[5], (const float*)d_in[7],
                                 (const float*)d_in[11], (const float*)d_in[13], (const float*)d_in[15], wfr);
    kdeg<<<NE / 256, 256, 0, stream>>>(eidx, cnt);
    kscan<<<1, 1024, 0, stream>>>(cnt, rowptr);
    kfill<<<NE / 256, 256, 0, stream>>>(eidx, cnt2, rowptr, perm);
    k1m<<<NE / 64, 256, 0, stream>>>(em, eidx, ef, wfr, b_le, perm, msg);
    k1g<<<NN / 4, 256, 0, stream>>>(rowptr, msg, nodebuf);
    k2<<<(NN + 63) / 64, 256, 0, stream>>>(em, nodebuf, wfr, b1, b2, sums);
    k3<<<(NN * 64) / 1024, 256, 0, stream>>>(nodebuf, sums, gx, bx, wsx);
    k4<<<NE / 128, 256, 0, stream>>>(eidx, ef, wsx, wfr, be1, be2, be3, eout, pws);
    k4r<<<128, 256, 0, stream>>>(pws, sums);
    k5<<<((size_t)NE * 64) / 1024, 256, 0, stream>>>(eout, sums, ge, be);
}

// Round 14
// 574.484 us; speedup vs baseline: 1.0015x; 1.0015x over previous
//
#include <hip/hip_runtime.h>
#include <cstddef>
#include <cstdint>

#define NN 50000
#define NE 800000

typedef __bf16 bf16x8 __attribute__((ext_vector_type(8)));
typedef float  f32x4  __attribute__((ext_vector_type(4)));

__device__ __forceinline__ bf16x8 ldfrag(const __bf16* __restrict__ wfr, int f, int lane) {
    return *reinterpret_cast<const bf16x8*>(wfr + (size_t)(f * 64 + lane) * 8);
}
__device__ __forceinline__ f32x4 mfma16(bf16x8 a, bf16x8 b, f32x4 c) {
    return __builtin_amdgcn_mfma_f32_16x16x32_bf16(a, b, c, 0, 0, 0);
}
__device__ __forceinline__ bool idx_is64(const int* eidx) {
    return ((eidx[1] | eidx[3] | eidx[5] | eidx[7]) == 0);
}
__device__ __forceinline__ int ld_src(const int* eidx, bool is64, int e) {
    return is64 ? eidx[(size_t)2 * e] : eidx[e];
}
__device__ __forceinline__ int ld_dst(const int* eidx, bool is64, int e) {
    return is64 ? eidx[2 * ((size_t)NE + e)] : eidx[(size_t)NE + e];
}
__device__ __forceinline__ bf16x8 cvt8(const float* __restrict__ p) {
    float4 v0 = *reinterpret_cast<const float4*>(p);
    float4 v1 = *reinterpret_cast<const float4*>(p + 4);
    bf16x8 r;
    r[0] = (__bf16)v0.x; r[1] = (__bf16)v0.y; r[2] = (__bf16)v0.z; r[3] = (__bf16)v0.w;
    r[4] = (__bf16)v1.x; r[5] = (__bf16)v1.y; r[6] = (__bf16)v1.z; r[7] = (__bf16)v1.w;
    return r;
}

// ---------------- weight prep: f32 [K][64] -> bf16 B-fragment layout ----------------
// frag(kt,nt): lane holds B[k = kt*32 + (lane>>4)*8 + b][n = nt*16 + (lane&15)], b=0..7
// table: W_le f0..7, W1 f8..15, W2 f16..23, We1 f24..47, We2 f48..55, We3 f56..63
__global__ __launch_bounds__(256) void prep(const float* __restrict__ wle, const float* __restrict__ w1,
                                            const float* __restrict__ w2, const float* __restrict__ we1,
                                            const float* __restrict__ we2, const float* __restrict__ we3,
                                            __bf16* __restrict__ wfr) {
    int sid = blockIdx.x * 256 + threadIdx.x;
    int f = sid >> 6, lane = sid & 63;
    const float* W; int fo;
    if (f < 8)       { W = wle; fo = 0; }
    else if (f < 16) { W = w1;  fo = 8; }
    else if (f < 24) { W = w2;  fo = 16; }
    else if (f < 48) { W = we1; fo = 24; }
    else if (f < 56) { W = we2; fo = 48; }
    else             { W = we3; fo = 56; }
    int lf = f - fo, kt = lf >> 2, nt = lf & 3;
    int g = lane >> 4, c = lane & 15;
#pragma unroll
    for (int b = 0; b < 8; b++) {
        int k = kt * 32 + g * 8 + b;
        int n = nt * 16 + c;
        wfr[(size_t)(f * 64 + lane) * 8 + b] = (__bf16)W[(size_t)k * 64 + n];
    }
}

// ---------------- CSR build: degree count -> scan -> slot fill (edge -> sorted position) ----------------
__global__ __launch_bounds__(256) void kdeg(const int* __restrict__ eidx, int* __restrict__ cnt) {
    const bool is64 = idx_is64(eidx);
    int e = blockIdx.x * 256 + threadIdx.x;
    atomicAdd(&cnt[ld_dst(eidx, is64, e)], 1);
}

__global__ __launch_bounds__(1024) void kscan(const int* __restrict__ cnt, int* __restrict__ rowptr) {
    __shared__ int ps[1024];
    const int t = threadIdx.x;
    const int CH = (NN + 1023) / 1024;  // 49
    const int b0 = t * CH;
    int s = 0;
    for (int i = 0; i < CH; i++) { int n = b0 + i; if (n < NN) s += cnt[n]; }
    ps[t] = s;
    __syncthreads();
    for (int off = 1; off < 1024; off <<= 1) {
        int v = (t >= off) ? ps[t - off] : 0;
        __syncthreads();
        ps[t] += v;
        __syncthreads();
    }
    int run = (t == 0) ? 0 : ps[t - 1];
    for (int i = 0; i < CH; i++) {
        int n = b0 + i;
        if (n < NN) { rowptr[n] = run; run += cnt[n]; }
    }
    if (t == 1023) rowptr[NN] = ps[1023];
}

__global__ __launch_bounds__(256) void kfill(const int* __restrict__ eidx, int* __restrict__ cnt2,
                                             const int* __restrict__ rowptr, int* __restrict__ perm) {
    const bool is64 = idx_is64(eidx);
    int e = blockIdx.x * 256 + threadIdx.x;
    int dn = ld_dst(eidx, is64, e);
    int slot = rowptr[dn] + atomicAdd(&cnt2[dn], 1);
    perm[e] = slot;   // edge e's row goes to sorted position slot
}

// ---------------- k1m: msg = relu(em[src] + ef@W_le + b_le); sequential compute, dst-sorted write ----------------
__global__ __launch_bounds__(256) void k1m(const float* __restrict__ em, const int* __restrict__ eidx,
                                           const float* __restrict__ ef, const __bf16* __restrict__ wfr,
                                           const float* __restrict__ ble, const int* __restrict__ perm,
                                           __bf16* __restrict__ msg) {
    __shared__ __bf16 Msh[4][16][72];
    const int t = threadIdx.x;
    const int base = blockIdx.x * 64;
    const int lane = t & 63, w = t >> 6, c = lane & 15, g = lane >> 4;
    const int erow = base + w * 16 + c;
    const bool is64 = idx_is64(eidx);
    bf16x8 a[2];
#pragma unroll
    for (int kt = 0; kt < 2; kt++)
        a[kt] = cvt8(ef + (size_t)erow * 64 + kt * 32 + g * 8);
    f32x4 acc[4] = {{0.f,0.f,0.f,0.f},{0.f,0.f,0.f,0.f},{0.f,0.f,0.f,0.f},{0.f,0.f,0.f,0.f}};
#pragma unroll
    for (int kt = 0; kt < 2; kt++)
#pragma unroll
        for (int nt = 0; nt < 4; nt++) acc[nt] = mfma16(a[kt], ldfrag(wfr, kt * 4 + nt, lane), acc[nt]);
#pragma unroll
    for (int rr = 0; rr < 4; rr++) {
        int e = base + w * 16 + g * 4 + rr;
        int sn = ld_src(eidx, is64, e);
#pragma unroll
        for (int nt = 0; nt < 4; nt++) {
            int col = nt * 16 + c;
            float v = acc[nt][rr] + ble[col] + em[(size_t)sn * 64 + col];
            Msh[w][g * 4 + rr][col] = (__bf16)(v > 0.f ? v : 0.f);  // wave-private slab
        }
    }
    // store: 8 lanes cover one 128B row; destination row = perm[edge] (dst-sorted position)
#pragma unroll
    for (int p = 0; p < 2; p++) {
        int r16 = p * 8 + (lane >> 3);
        int e = base + w * 16 + r16;
        size_t drow = (size_t)perm[e];
        bf16x8 mv = *reinterpret_cast<const bf16x8*>(&Msh[w][r16][(lane & 7) * 8]);
        *reinterpret_cast<bf16x8*>(msg + drow * 64 + (lane & 7) * 8) = mv;
    }
}

// ---------------- k1g: aggr[n] = sum over contiguous sorted run [rowptr[n], rowptr[n+1]) ----------------
__global__ __launch_bounds__(256) void k1g(const int* __restrict__ rowptr, const __bf16* __restrict__ msg,
                                           float* __restrict__ nodebuf) {
    const int t = threadIdx.x, lane = t & 63, w = t >> 6;
    const int n = blockIdx.x * 4 + w;
    const int s0 = rowptr[n], s1 = rowptr[n + 1];
    const int q = lane >> 3, r = lane & 7;
    float acc[8] = {0.f,0.f,0.f,0.f,0.f,0.f,0.f,0.f};
    for (int j = s0; j < s1; j += 8) {
        int jj = j + q;
        if (jj < s1) {
            bf16x8 m = *reinterpret_cast<const bf16x8*>(msg + (size_t)jj * 64 + r * 8);
#pragma unroll
            for (int i = 0; i < 8; i++) acc[i] += (float)m[i];
        }
    }
#pragma unroll
    for (int mask = 8; mask <= 32; mask <<= 1)
#pragma unroll
        for (int i = 0; i < 8; i++) acc[i] += __shfl_xor(acc[i], mask);
    if (lane < 8) {
        *reinterpret_cast<float4*>(nodebuf + (size_t)n * 64 + lane * 8)     = make_float4(acc[0], acc[1], acc[2], acc[3]);
        *reinterpret_cast<float4*>(nodebuf + (size_t)n * 64 + lane * 8 + 4) = make_float4(acc[4], acc[5], acc[6], acc[7]);
    }
}

// ---------------- k2: h = em + aggr; h2 = relu(h@W1+b1)@W2+b2 (in-place); BN partial sums ----------------
__global__ __launch_bounds__(256) void k2(const float* __restrict__ em, float* __restrict__ nb,
                                          const __bf16* __restrict__ wfr, const float* __restrict__ b1,
                                          const float* __restrict__ b2, float* __restrict__ sums) {
    __shared__ __bf16 Ysh[64][72];
    __shared__ float bs[128];
    const int t = threadIdx.x;
    const int base = blockIdx.x * 64;
    if (t < 128) bs[t] = 0.f;
    __syncthreads();
    const int lane = t & 63, w = t >> 6, c = lane & 15, g = lane >> 4;
    const int arow = base + w * 16 + c;
    const size_t rl = (size_t)(arow < NN ? arow : NN - 1) * 64;
    bf16x8 a[2];
#pragma unroll
    for (int kt = 0; kt < 2; kt++) {
        int off = kt * 32 + g * 8;
        float4 e0 = *reinterpret_cast<const float4*>(em + rl + off);
        float4 e1 = *reinterpret_cast<const float4*>(em + rl + off + 4);
        float4 n0 = *reinterpret_cast<const float4*>(nb + rl + off);
        float4 n1 = *reinterpret_cast<const float4*>(nb + rl + off + 4);
        bf16x8 r;
        r[0] = (__bf16)(e0.x + n0.x); r[1] = (__bf16)(e0.y + n0.y);
        r[2] = (__bf16)(e0.z + n0.z); r[3] = (__bf16)(e0.w + n0.w);
        r[4] = (__bf16)(e1.x + n1.x); r[5] = (__bf16)(e1.y + n1.y);
        r[6] = (__bf16)(e1.z + n1.z); r[7] = (__bf16)(e1.w + n1.w);
        a[kt] = r;
    }
    f32x4 a1[4] = {{0.f,0.f,0.f,0.f},{0.f,0.f,0.f,0.f},{0.f,0.f,0.f,0.f},{0.f,0.f,0.f,0.f}};
#pragma unroll
    for (int kt = 0; kt < 2; kt++)
#pragma unroll
        for (int nt = 0; nt < 4; nt++) a1[nt] = mfma16(a[kt], ldfrag(wfr, 8 + kt * 4 + nt, lane), a1[nt]);
#pragma unroll
    for (int nt = 0; nt < 4; nt++) {
        float bb = b1[nt * 16 + c];
#pragma unroll
        for (int rr = 0; rr < 4; rr++) {
            float v = a1[nt][rr] + bb;
            v = v > 0.f ? v : 0.f;
            Ysh[w * 16 + g * 4 + rr][nt * 16 + c] = (__bf16)v;  // wave-private slab
        }
    }
    bf16x8 ya[2];
#pragma unroll
    for (int kt = 0; kt < 2; kt++)
        ya[kt] = *reinterpret_cast<const bf16x8*>(&Ysh[w * 16 + c][kt * 32 + g * 8]);
    f32x4 a2[4] = {{0.f,0.f,0.f,0.f},{0.f,0.f,0.f,0.f},{0.f,0.f,0.f,0.f},{0.f,0.f,0.f,0.f}};
#pragma unroll
    for (int kt = 0; kt < 2; kt++)
#pragma unroll
        for (int nt = 0; nt < 4; nt++) a2[nt] = mfma16(ya[kt], ldfrag(wfr, 16 + kt * 4 + nt, lane), a2[nt]);
#pragma unroll
    for (int nt = 0; nt < 4; nt++) {
        int col = nt * 16 + c;
        float bb = b2[col];
        float ss = 0.f, qq = 0.f;
#pragma unroll
        for (int rr = 0; rr < 4; rr++) {
            int row = base + w * 16 + g * 4 + rr;
            if (row < NN) {
                float v = a2[nt][rr] + bb;
                nb[(size_t)row * 64 + col] = v;
                ss += v; qq += v * v;
            }
        }
        ss += __shfl_xor(ss, 16); ss += __shfl_xor(ss, 32);
        qq += __shfl_xor(qq, 16); qq += __shfl_xor(qq, 32);
        if (g == 0) { atomicAdd(&bs[col], ss); atomicAdd(&bs[64 + col], qq); }
    }
    __syncthreads();
    if (t < 128) atomicAdd(&sums[t], bs[t]);
}

// ---------------- k3: x = relu(BN(h2)) in-place; also bf16 copy for gathers ----------------
__global__ __launch_bounds__(256) void k3(float* __restrict__ nb, const float* __restrict__ sums,
                                          const float* __restrict__ gx, const float* __restrict__ bx,
                                          __bf16* __restrict__ wsx) {
    size_t i4 = (size_t)(blockIdx.x * 256 + threadIdx.x) * 4;
    int col0 = (int)(i4 & 63);
    float4 v = *reinterpret_cast<const float4*>(nb + i4);
    const float* pv = reinterpret_cast<const float*>(&v);
    float o[4]; short so[4];
#pragma unroll
    for (int j = 0; j < 4; j++) {
        int col = col0 + j;
        float m   = sums[col] * (1.0f / 50000.0f);
        float var = sums[64 + col] * (1.0f / 50000.0f) - m * m;
        float inv = rsqrtf(var + 1e-5f);
        float x = (pv[j] - m) * inv * gx[col] + bx[col];
        x = x > 0.f ? x : 0.f;
        o[j] = x;
        so[j] = __builtin_bit_cast(short, (__bf16)x);
    }
    *reinterpret_cast<float4*>(nb + i4) = make_float4(o[0], o[1], o[2], o[3]);
    *reinterpret_cast<short4*>(wsx + i4) = make_short4(so[0], so[1], so[2], so[3]);
}

// ---------------- k4: fused 3-layer edge MLP, TWO 64-edge tiles per block (latency-hiding ILP) ----------------
__global__ __launch_bounds__(256) void k4(const int* __restrict__ eidx, const float* __restrict__ ef,
                                          const __bf16* __restrict__ wsx, const __bf16* __restrict__ wfr,
                                          const float* __restrict__ be1, const float* __restrict__ be2,
                                          const float* __restrict__ be3, float* __restrict__ eout,
                                          float* __restrict__ pws) {
    __shared__ __bf16 Ysh[2][64][72];
    __shared__ float bs[128];
    const int t = threadIdx.x;
    const int blockb = blockIdx.x * 128;
    if (t < 128) bs[t] = 0.f;
    __syncthreads();
    const int lane = t & 63, w = t >> 6, c = lane & 15, g = lane >> 4;
    const bool is64 = idx_is64(eidx);

    int erow[2], sn[2], dn[2];
    bf16x8 xs[2][2], xd[2][2], ea[2][2];
#pragma unroll
    for (int tt = 0; tt < 2; tt++) {
        erow[tt] = blockb + tt * 64 + w * 16 + c;
        sn[tt] = ld_src(eidx, is64, erow[tt]);
        dn[tt] = ld_dst(eidx, is64, erow[tt]);
#pragma unroll
        for (int kt = 0; kt < 2; kt++) {
            int off = kt * 32 + g * 8;
            xs[tt][kt] = *reinterpret_cast<const bf16x8*>(wsx + (size_t)sn[tt] * 64 + off);
            xd[tt][kt] = *reinterpret_cast<const bf16x8*>(wsx + (size_t)dn[tt] * 64 + off);
            ea[tt][kt] = cvt8(ef + (size_t)erow[tt] * 64 + off);
        }
    }
    f32x4 a1[2][4];
#pragma unroll
    for (int tt = 0; tt < 2; tt++)
#pragma unroll
        for (int nt = 0; nt < 4; nt++) a1[tt][nt] = f32x4{0.f,0.f,0.f,0.f};
#pragma unroll
    for (int tt = 0; tt < 2; tt++)
#pragma unroll
        for (int kt = 0; kt < 2; kt++)
#pragma unroll
            for (int nt = 0; nt < 4; nt++) a1[tt][nt] = mfma16(xs[tt][kt], ldfrag(wfr, 24 + kt * 4 + nt, lane), a1[tt][nt]);
#pragma unroll
    for (int tt = 0; tt < 2; tt++)
#pragma unroll
        for (int kt = 0; kt < 2; kt++)
#pragma unroll
            for (int nt = 0; nt < 4; nt++) a1[tt][nt] = mfma16(xd[tt][kt], ldfrag(wfr, 32 + kt * 4 + nt, lane), a1[tt][nt]);
#pragma unroll
    for (int tt = 0; tt < 2; tt++)
#pragma unroll
        for (int kt = 0; kt < 2; kt++)
#pragma unroll
            for (int nt = 0; nt < 4; nt++) a1[tt][nt] = mfma16(ea[tt][kt], ldfrag(wfr, 40 + kt * 4 + nt, lane), a1[tt][nt]);
#pragma unroll
    for (int tt = 0; tt < 2; tt++)
#pragma unroll
        for (int nt = 0; nt < 4; nt++) {
            float bb = be1[nt * 16 + c];
#pragma unroll
            for (int rr = 0; rr < 4; rr++) {
                float v = a1[tt][nt][rr] + bb;
                v = v > 0.f ? v : 0.f;
                Ysh[tt][w * 16 + g * 4 + rr][nt * 16 + c] = (__bf16)v;  // wave-private slab
            }
        }
    bf16x8 ya[2][2];
#pragma unroll
    for (int tt = 0; tt < 2; tt++)
#pragma unroll
        for (int kt = 0; kt < 2; kt++)
            ya[tt][kt] = *reinterpret_cast<const bf16x8*>(&Ysh[tt][w * 16 + c][kt * 32 + g * 8]);
    f32x4 a2[2][4];
#pragma unroll
    for (int tt = 0; tt < 2; tt++)
#pragma unroll
        for (int nt = 0; nt < 4; nt++) a2[tt][nt] = f32x4{0.f,0.f,0.f,0.f};
#pragma unroll
    for (int tt = 0; tt < 2; tt++)
#pragma unroll
        for (int kt = 0; kt < 2; kt++)
#pragma unroll
            for (int nt = 0; nt < 4; nt++) a2[tt][nt] = mfma16(ya[tt][kt], ldfrag(wfr, 48 + kt * 4 + nt, lane), a2[tt][nt]);
#pragma unroll
    for (int tt = 0; tt < 2; tt++)
#pragma unroll
        for (int nt = 0; nt < 4; nt++) {
            float bb = be2[nt * 16 + c];
#pragma unroll
            for (int rr = 0; rr < 4; rr++) {
                float v = a2[tt][nt][rr] + bb;
                v = v > 0.f ? v : 0.f;
                Ysh[tt][w * 16 + g * 4 + rr][nt * 16 + c] = (__bf16)v;  // overwrite own slab
            }
        }
#pragma unroll
    for (int tt = 0; tt < 2; tt++)
#pragma unroll
        for (int kt = 0; kt < 2; kt++)
            ya[tt][kt] = *reinterpret_cast<const bf16x8*>(&Ysh[tt][w * 16 + c][kt * 32 + g * 8]);
    f32x4 a3[2][4];
#pragma unroll
    for (int tt = 0; tt < 2; tt++)
#pragma unroll
        for (int nt = 0; nt < 4; nt++) a3[tt][nt] = f32x4{0.f,0.f,0.f,0.f};
#pragma unroll
    for (int tt = 0; tt < 2; tt++)
#pragma unroll
        for (int kt = 0; kt < 2; kt++)
#pragma unroll
            for (int nt = 0; nt < 4; nt++) a3[tt][nt] = mfma16(ya[tt][kt], ldfrag(wfr, 56 + kt * 4 + nt, lane), a3[tt][nt]);
#pragma unroll
    for (int tt = 0; tt < 2; tt++)
#pragma unroll
        for (int nt = 0; nt < 4; nt++) {
            int col = nt * 16 + c;
            float bb = be3[col];
            float ss = 0.f, qq = 0.f;
#pragma unroll
            for (int rr = 0; rr < 4; rr++) {
                int e = blockb + tt * 64 + w * 16 + g * 4 + rr;
                float v = a3[tt][nt][rr] + bb;
                eout[(size_t)e * 64 + col] = v;
                ss += v; qq += v * v;
            }
            ss += __shfl_xor(ss, 16); ss += __shfl_xor(ss, 32);
            qq += __shfl_xor(qq, 16); qq += __shfl_xor(qq, 32);
            if (g == 0) { atomicAdd(&bs[col], ss); atomicAdd(&bs[64 + col], qq); }
        }
    __syncthreads();
    if (t < 128) pws[(size_t)t * (NE / 128) + blockIdx.x] = bs[t];
}

// ---------------- k4r: reduce per-block partials -> edge BN sums ----------------
__global__ __launch_bounds__(256) void k4r(const float* __restrict__ pws, float* __restrict__ sums) {
    int b = blockIdx.x;
    float s = 0.f;
    for (int i = threadIdx.x; i < NE / 128; i += 256) s += pws[(size_t)b * (NE / 128) + i];
#pragma unroll
    for (int m = 32; m >= 1; m >>= 1) s += __shfl_xor(s, m);
    __shared__ float acc4[4];
    int lane = threadIdx.x & 63, wid = threadIdx.x >> 6;
    if (lane == 0) acc4[wid] = s;
    __syncthreads();
    if (threadIdx.x == 0) sums[128 + b] = acc4[0] + acc4[1] + acc4[2] + acc4[3];
}

// ---------------- k5: edge_out = relu(BN(e3)) in-place ----------------
__global__ __launch_bounds__(256) void k5(float* __restrict__ eo, const float* __restrict__ sums,
                                          const float* __restrict__ ge, const float* __restrict__ be) {
    size_t i4 = (size_t)(blockIdx.x * 256 + threadIdx.x) * 4;
    int col0 = (int)(i4 & 63);
    float4 v = *reinterpret_cast<const float4*>(eo + i4);
    const float* pv = reinterpret_cast<const float*>(&v);
    float o[4];
#pragma unroll
    for (int j = 0; j < 4; j++) {
        int col = col0 + j;
        float m   = sums[128 + col] * (1.0f / 800000.0f);
        float var = sums[192 + col] * (1.0f / 800000.0f) - m * m;
        float inv = rsqrtf(var + 1e-5f);
        float x = (pv[j] - m) * inv * ge[col] + be[col];
        o[j] = x > 0.f ? x : 0.f;
    }
    *reinterpret_cast<float4*>(eo + i4) = make_float4(o[0], o[1], o[2], o[3]);
}

extern "C" void kernel_launch(void* const* d_in, const int* in_sizes, int n_in,
                              void* d_out, int out_size, void* d_ws, size_t ws_size,
                              hipStream_t stream) {
    const float* em   = (const float*)d_in[0];
    const int*   eidx = (const int*)d_in[1];
    const float* ef   = (const float*)d_in[2];
    const float* b_le = (const float*)d_in[4];
    const float* b1   = (const float*)d_in[6];
    const float* b2   = (const float*)d_in[8];
    const float* gx   = (const float*)d_in[9];
    const float* bx   = (const float*)d_in[10];
    const float* be1  = (const float*)d_in[12];
    const float* be2  = (const float*)d_in[14];
    const float* be3  = (const float*)d_in[16];
    const float* ge   = (const float*)d_in[17];
    const float* be   = (const float*)d_in[18];

    float* out = (float*)d_out;
    float* nodebuf = out;                          // 50000*64 f32 (aggr -> h2 -> x_em in place)
    float* eout = out + (size_t)NN * 64;           // 800000*64 f32 (e3 -> edge_out in place)

    // ws layout (bytes):
    // sums 1KB | wfr 64KB | wsx 6.4MB | csr { cnt 200K, cnt2 200K, rowptr 200K, perm 3.2MB } | msg 102.4MB
    // pws (3.2MB, used by k4/k4r) ALIASES the csr region — disjoint lifetimes (csr dead after k1g).
    char* wsb = (char*)d_ws;
    float*  sums   = (float*)wsb;
    __bf16* wfr    = (__bf16*)(wsb + 1024);
    __bf16* wsx    = (__bf16*)(wsb + 1024 + 65536);
    size_t  off    = 1024 + 65536 + (size_t)NN * 64 * 2;   // 6,466,560
    char*   csrb   = wsb + off;
    int*    cnt    = (int*)(csrb);
    int*    cnt2   = (int*)(csrb + 200192);
    int*    rowptr = (int*)(csrb + 2 * 200192);
    int*    perm   = (int*)(csrb + 3 * 200192);
    float*  pws    = (float*)csrb;                          // alias: k4 phase only
    __bf16* msg    = (__bf16*)(csrb + 3 * 200192 + (size_t)NE * 4);

    hipMemsetAsync(sums, 0, 256 * sizeof(float), stream);
    hipMemsetAsync(cnt, 0, 200192 * 2, stream);    // cnt + cnt2

    prep<<<16, 256, 0, stream>>>((const float*)d_in[3], (const float*)d_in[5], (const float*)d_in[7],
                                 (const float*)d_in[11], (const float*)d_in[13], (const float*)d_in[15], wfr);
    kdeg<<<NE / 256, 256, 0, stream>>>(eidx, cnt);
    kscan<<<1, 1024, 0, stream>>>(cnt, rowptr);
    kfill<<<NE / 256, 256, 0, stream>>>(eidx, cnt2, rowptr, perm);
    k1m<<<NE / 64, 256, 0, stream>>>(em, eidx, ef, wfr, b_le, perm, msg);
    k1g<<<NN / 4, 256, 0, stream>>>(rowptr, msg, nodebuf);
    k2<<<(NN + 63) / 64, 256, 0, stream>>>(em, nodebuf, wfr, b1, b2, sums);
    k3<<<(NN * 64) / 1024, 256, 0, stream>>>(nodebuf, sums, gx, bx, wsx);
    k4<<<NE / 128, 256, 0, stream>>>(eidx, ef, wsx, wfr, be1, be2, be3, eout, pws);
    k4r<<<128, 256, 0, stream>>>(pws, sums);
    k5<<<((size_t)NE * 64) / 1024, 256, 0, stream>>>(eout, sums, ge, be);
}

// Round 15
// 440.455 us; speedup vs baseline: 1.3063x; 1.3043x over previous
//
#include <hip/hip_runtime.h>
#include <cstddef>
#include <cstdint>

#define NN 50000
#define NE 800000

typedef __bf16 bf16x8 __attribute__((ext_vector_type(8)));
typedef float  f32x4  __attribute__((ext_vector_type(4)));

__device__ __forceinline__ bf16x8 ldfrag(const __bf16* __restrict__ wfr, int f, int lane) {
    return *reinterpret_cast<const bf16x8*>(wfr + (size_t)(f * 64 + lane) * 8);
}
__device__ __forceinline__ f32x4 mfma16(bf16x8 a, bf16x8 b, f32x4 c) {
    return __builtin_amdgcn_mfma_f32_16x16x32_bf16(a, b, c, 0, 0, 0);
}
__device__ __forceinline__ bool idx_is64(const int* eidx) {
    return ((eidx[1] | eidx[3] | eidx[5] | eidx[7]) == 0);
}
__device__ __forceinline__ int ld_src(const int* eidx, bool is64, int e) {
    return is64 ? eidx[(size_t)2 * e] : eidx[e];
}
__device__ __forceinline__ int ld_dst(const int* eidx, bool is64, int e) {
    return is64 ? eidx[2 * ((size_t)NE + e)] : eidx[(size_t)NE + e];
}
__device__ __forceinline__ bf16x8 cvt8(const float* __restrict__ p) {
    float4 v0 = *reinterpret_cast<const float4*>(p);
    float4 v1 = *reinterpret_cast<const float4*>(p + 4);
    bf16x8 r;
    r[0] = (__bf16)v0.x; r[1] = (__bf16)v0.y; r[2] = (__bf16)v0.z; r[3] = (__bf16)v0.w;
    r[4] = (__bf16)v1.x; r[5] = (__bf16)v1.y; r[6] = (__bf16)v1.z; r[7] = (__bf16)v1.w;
    return r;
}

// ---------------- weight prep: f32 [K][64] -> bf16 B-fragment layout; block 0 zeroes sums ----------------
// frag(kt,nt): lane holds B[k = kt*32 + (lane>>4)*8 + b][n = nt*16 + (lane&15)], b=0..7
// table: W_le f0..7, W1 f8..15, W2 f16..23, We1 f24..47, We2 f48..55, We3 f56..63
__global__ __launch_bounds__(256) void prep(const float* __restrict__ wle, const float* __restrict__ w1,
                                            const float* __restrict__ w2, const float* __restrict__ we1,
                                            const float* __restrict__ we2, const float* __restrict__ we3,
                                            __bf16* __restrict__ wfr, float* __restrict__ sums) {
    if (blockIdx.x == 0) sums[threadIdx.x] = 0.f;   // 256 floats: node + edge BN accumulators
    int sid = blockIdx.x * 256 + threadIdx.x;
    int f = sid >> 6, lane = sid & 63;
    const float* W; int fo;
    if (f < 8)       { W = wle; fo = 0; }
    else if (f < 16) { W = w1;  fo = 8; }
    else if (f < 24) { W = w2;  fo = 16; }
    else if (f < 48) { W = we1; fo = 24; }
    else if (f < 56) { W = we2; fo = 48; }
    else             { W = we3; fo = 56; }
    int lf = f - fo, kt = lf >> 2, nt = lf & 3;
    int g = lane >> 4, c = lane & 15;
#pragma unroll
    for (int b = 0; b < 8; b++) {
        int k = kt * 32 + g * 8 + b;
        int n = nt * 16 + c;
        wfr[(size_t)(f * 64 + lane) * 8 + b] = (__bf16)W[(size_t)k * 64 + n];
    }
}

// ---------------- k1: msg = relu(em[src] + ef@W_le + b_le); atomic scatter (measured-best) ----------------
__global__ __launch_bounds__(256) void k1(const float* __restrict__ em, const int* __restrict__ eidx,
                                          const float* __restrict__ ef, const __bf16* __restrict__ wfr,
                                          const float* __restrict__ ble, float* __restrict__ nodebuf) {
    __shared__ __bf16 Ash[64][72];
    const int t = threadIdx.x;
    const int base = blockIdx.x * 64;
    {
        const int r = t >> 2, seg = t & 3;
        const float4* p = reinterpret_cast<const float4*>(ef + (size_t)(base + r) * 64 + seg * 16);
#pragma unroll
        for (int i = 0; i < 4; i++) {
            float4 v = p[i];
            int cb = seg * 16 + i * 4;
            Ash[r][cb + 0] = (__bf16)v.x; Ash[r][cb + 1] = (__bf16)v.y;
            Ash[r][cb + 2] = (__bf16)v.z; Ash[r][cb + 3] = (__bf16)v.w;
        }
    }
    const bool is64 = idx_is64(eidx);
    __syncthreads();
    const int lane = t & 63, w = t >> 6, c = lane & 15, g = lane >> 4;
    const int arow = w * 16 + c;
    f32x4 acc[4] = {{0.f,0.f,0.f,0.f},{0.f,0.f,0.f,0.f},{0.f,0.f,0.f,0.f},{0.f,0.f,0.f,0.f}};
#pragma unroll
    for (int kt = 0; kt < 2; kt++) {
        bf16x8 a = *reinterpret_cast<const bf16x8*>(&Ash[arow][kt * 32 + g * 8]);
#pragma unroll
        for (int nt = 0; nt < 4; nt++) acc[nt] = mfma16(a, ldfrag(wfr, kt * 4 + nt, lane), acc[nt]);
    }
#pragma unroll
    for (int rr = 0; rr < 4; rr++) {
        int e = base + w * 16 + g * 4 + rr;
        int sn = ld_src(eidx, is64, e);
        int dn = ld_dst(eidx, is64, e);
#pragma unroll
        for (int nt = 0; nt < 4; nt++) {
            int col = nt * 16 + c;
            float v = acc[nt][rr] + ble[col] + em[(size_t)sn * 64 + col];
            if (v > 0.f) atomicAdd(&nodebuf[(size_t)dn * 64 + col], v);
        }
    }
}

// ---------------- k2: h = em + aggr; h2 = relu(h@W1+b1)@W2+b2 (in-place); BN partial sums ----------------
__global__ __launch_bounds__(256) void k2(const float* __restrict__ em, float* __restrict__ nb,
                                          const __bf16* __restrict__ wfr, const float* __restrict__ b1,
                                          const float* __restrict__ b2, float* __restrict__ sums) {
    __shared__ __bf16 Ysh[64][72];
    __shared__ float bs[128];
    const int t = threadIdx.x;
    const int base = blockIdx.x * 64;
    if (t < 128) bs[t] = 0.f;
    __syncthreads();
    const int lane = t & 63, w = t >> 6, c = lane & 15, g = lane >> 4;
    const int arow = base + w * 16 + c;
    const size_t rl = (size_t)(arow < NN ? arow : NN - 1) * 64;
    bf16x8 a[2];
#pragma unroll
    for (int kt = 0; kt < 2; kt++) {
        int off = kt * 32 + g * 8;
        float4 e0 = *reinterpret_cast<const float4*>(em + rl + off);
        float4 e1 = *reinterpret_cast<const float4*>(em + rl + off + 4);
        float4 n0 = *reinterpret_cast<const float4*>(nb + rl + off);
        float4 n1 = *reinterpret_cast<const float4*>(nb + rl + off + 4);
        bf16x8 r;
        r[0] = (__bf16)(e0.x + n0.x); r[1] = (__bf16)(e0.y + n0.y);
        r[2] = (__bf16)(e0.z + n0.z); r[3] = (__bf16)(e0.w + n0.w);
        r[4] = (__bf16)(e1.x + n1.x); r[5] = (__bf16)(e1.y + n1.y);
        r[6] = (__bf16)(e1.z + n1.z); r[7] = (__bf16)(e1.w + n1.w);
        a[kt] = r;
    }
    f32x4 a1[4] = {{0.f,0.f,0.f,0.f},{0.f,0.f,0.f,0.f},{0.f,0.f,0.f,0.f},{0.f,0.f,0.f,0.f}};
#pragma unroll
    for (int kt = 0; kt < 2; kt++)
#pragma unroll
        for (int nt = 0; nt < 4; nt++) a1[nt] = mfma16(a[kt], ldfrag(wfr, 8 + kt * 4 + nt, lane), a1[nt]);
#pragma unroll
    for (int nt = 0; nt < 4; nt++) {
        float bb = b1[nt * 16 + c];
#pragma unroll
        for (int rr = 0; rr < 4; rr++) {
            float v = a1[nt][rr] + bb;
            v = v > 0.f ? v : 0.f;
            Ysh[w * 16 + g * 4 + rr][nt * 16 + c] = (__bf16)v;  // wave-private slab
        }
    }
    bf16x8 ya[2];
#pragma unroll
    for (int kt = 0; kt < 2; kt++)
        ya[kt] = *reinterpret_cast<const bf16x8*>(&Ysh[w * 16 + c][kt * 32 + g * 8]);
    f32x4 a2[4] = {{0.f,0.f,0.f,0.f},{0.f,0.f,0.f,0.f},{0.f,0.f,0.f,0.f},{0.f,0.f,0.f,0.f}};
#pragma unroll
    for (int kt = 0; kt < 2; kt++)
#pragma unroll
        for (int nt = 0; nt < 4; nt++) a2[nt] = mfma16(ya[kt], ldfrag(wfr, 16 + kt * 4 + nt, lane), a2[nt]);
#pragma unroll
    for (int nt = 0; nt < 4; nt++) {
        int col = nt * 16 + c;
        float bb = b2[col];
        float ss = 0.f, qq = 0.f;
#pragma unroll
        for (int rr = 0; rr < 4; rr++) {
            int row = base + w * 16 + g * 4 + rr;
            if (row < NN) {
                float v = a2[nt][rr] + bb;
                nb[(size_t)row * 64 + col] = v;
                ss += v; qq += v * v;
            }
        }
        ss += __shfl_xor(ss, 16); ss += __shfl_xor(ss, 32);
        qq += __shfl_xor(qq, 16); qq += __shfl_xor(qq, 32);
        if (g == 0) { atomicAdd(&bs[col], ss); atomicAdd(&bs[64 + col], qq); }
    }
    __syncthreads();
    if (t < 128) atomicAdd(&sums[t], bs[t]);
}

// ---------------- k3: x = relu(BN(h2)) in-place; also bf16 copy for gathers ----------------
__global__ __launch_bounds__(256) void k3(float* __restrict__ nb, const float* __restrict__ sums,
                                          const float* __restrict__ gx, const float* __restrict__ bx,
                                          __bf16* __restrict__ wsx) {
    size_t i4 = (size_t)(blockIdx.x * 256 + threadIdx.x) * 4;
    int col0 = (int)(i4 & 63);
    float4 v = *reinterpret_cast<const float4*>(nb + i4);
    const float* pv = reinterpret_cast<const float*>(&v);
    float o[4]; short so[4];
#pragma unroll
    for (int j = 0; j < 4; j++) {
        int col = col0 + j;
        float m   = sums[col] * (1.0f / 50000.0f);
        float var = sums[64 + col] * (1.0f / 50000.0f) - m * m;
        float inv = rsqrtf(var + 1e-5f);
        float x = (pv[j] - m) * inv * gx[col] + bx[col];
        x = x > 0.f ? x : 0.f;
        o[j] = x;
        so[j] = __builtin_bit_cast(short, (__bf16)x);
    }
    *reinterpret_cast<float4*>(nb + i4) = make_float4(o[0], o[1], o[2], o[3]);
    *reinterpret_cast<short4*>(wsx + i4) = make_short4(so[0], so[1], so[2], so[3]);
}

// ---------------- k4: fused 3-layer edge MLP, TWO 64-edge tiles per block; setprio + NT stores ----------------
__global__ __launch_bounds__(256) void k4(const int* __restrict__ eidx, const float* __restrict__ ef,
                                          const __bf16* __restrict__ wsx, const __bf16* __restrict__ wfr,
                                          const float* __restrict__ be1, const float* __restrict__ be2,
                                          const float* __restrict__ be3, float* __restrict__ eout,
                                          float* __restrict__ pws) {
    __shared__ __bf16 Ysh[2][64][72];
    __shared__ float bs[128];
    const int t = threadIdx.x;
    const int blockb = blockIdx.x * 128;
    if (t < 128) bs[t] = 0.f;
    __syncthreads();
    const int lane = t & 63, w = t >> 6, c = lane & 15, g = lane >> 4;
    const bool is64 = idx_is64(eidx);

    int erow[2], sn[2], dn[2];
    bf16x8 xs[2][2], xd[2][2], ea[2][2];
#pragma unroll
    for (int tt = 0; tt < 2; tt++) {
        erow[tt] = blockb + tt * 64 + w * 16 + c;
        sn[tt] = ld_src(eidx, is64, erow[tt]);
        dn[tt] = ld_dst(eidx, is64, erow[tt]);
#pragma unroll
        for (int kt = 0; kt < 2; kt++) {
            int off = kt * 32 + g * 8;
            xs[tt][kt] = *reinterpret_cast<const bf16x8*>(wsx + (size_t)sn[tt] * 64 + off);
            xd[tt][kt] = *reinterpret_cast<const bf16x8*>(wsx + (size_t)dn[tt] * 64 + off);
            ea[tt][kt] = cvt8(ef + (size_t)erow[tt] * 64 + off);
        }
    }
    f32x4 a1[2][4];
#pragma unroll
    for (int tt = 0; tt < 2; tt++)
#pragma unroll
        for (int nt = 0; nt < 4; nt++) a1[tt][nt] = f32x4{0.f,0.f,0.f,0.f};
    __builtin_amdgcn_s_setprio(1);
#pragma unroll
    for (int tt = 0; tt < 2; tt++)
#pragma unroll
        for (int kt = 0; kt < 2; kt++)
#pragma unroll
            for (int nt = 0; nt < 4; nt++) a1[tt][nt] = mfma16(xs[tt][kt], ldfrag(wfr, 24 + kt * 4 + nt, lane), a1[tt][nt]);
#pragma unroll
    for (int tt = 0; tt < 2; tt++)
#pragma unroll
        for (int kt = 0; kt < 2; kt++)
#pragma unroll
            for (int nt = 0; nt < 4; nt++) a1[tt][nt] = mfma16(xd[tt][kt], ldfrag(wfr, 32 + kt * 4 + nt, lane), a1[tt][nt]);
#pragma unroll
    for (int tt = 0; tt < 2; tt++)
#pragma unroll
        for (int kt = 0; kt < 2; kt++)
#pragma unroll
            for (int nt = 0; nt < 4; nt++) a1[tt][nt] = mfma16(ea[tt][kt], ldfrag(wfr, 40 + kt * 4 + nt, lane), a1[tt][nt]);
    __builtin_amdgcn_s_setprio(0);
#pragma unroll
    for (int tt = 0; tt < 2; tt++)
#pragma unroll
        for (int nt = 0; nt < 4; nt++) {
            float bb = be1[nt * 16 + c];
#pragma unroll
            for (int rr = 0; rr < 4; rr++) {
                float v = a1[tt][nt][rr] + bb;
                v = v > 0.f ? v : 0.f;
                Ysh[tt][w * 16 + g * 4 + rr][nt * 16 + c] = (__bf16)v;  // wave-private slab
            }
        }
    bf16x8 ya[2][2];
#pragma unroll
    for (int tt = 0; tt < 2; tt++)
#pragma unroll
        for (int kt = 0; kt < 2; kt++)
            ya[tt][kt] = *reinterpret_cast<const bf16x8*>(&Ysh[tt][w * 16 + c][kt * 32 + g * 8]);
    f32x4 a2[2][4];
#pragma unroll
    for (int tt = 0; tt < 2; tt++)
#pragma unroll
        for (int nt = 0; nt < 4; nt++) a2[tt][nt] = f32x4{0.f,0.f,0.f,0.f};
    __builtin_amdgcn_s_setprio(1);
#pragma unroll
    for (int tt = 0; tt < 2; tt++)
#pragma unroll
        for (int kt = 0; kt < 2; kt++)
#pragma unroll
            for (int nt = 0; nt < 4; nt++) a2[tt][nt] = mfma16(ya[tt][kt], ldfrag(wfr, 48 + kt * 4 + nt, lane), a2[tt][nt]);
    __builtin_amdgcn_s_setprio(0);
#pragma unroll
    for (int tt = 0; tt < 2; tt++)
#pragma unroll
        for (int nt = 0; nt < 4; nt++) {
            float bb = be2[nt * 16 + c];
#pragma unroll
            for (int rr = 0; rr < 4; rr++) {
                float v = a2[tt][nt][rr] + bb;
                v = v > 0.f ? v : 0.f;
                Ysh[tt][w * 16 + g * 4 + rr][nt * 16 + c] = (__bf16)v;  // overwrite own slab
            }
        }
#pragma unroll
    for (int tt = 0; tt < 2; tt++)
#pragma unroll
        for (int kt = 0; kt < 2; kt++)
            ya[tt][kt] = *reinterpret_cast<const bf16x8*>(&Ysh[tt][w * 16 + c][kt * 32 + g * 8]);
    f32x4 a3[2][4];
#pragma unroll
    for (int tt = 0; tt < 2; tt++)
#pragma unroll
        for (int nt = 0; nt < 4; nt++) a3[tt][nt] = f32x4{0.f,0.f,0.f,0.f};
    __builtin_amdgcn_s_setprio(1);
#pragma unroll
    for (int tt = 0; tt < 2; tt++)
#pragma unroll
        for (int kt = 0; kt < 2; kt++)
#pragma unroll
            for (int nt = 0; nt < 4; nt++) a3[tt][nt] = mfma16(ya[tt][kt], ldfrag(wfr, 56 + kt * 4 + nt, lane), a3[tt][nt]);
    __builtin_amdgcn_s_setprio(0);
#pragma unroll
    for (int tt = 0; tt < 2; tt++)
#pragma unroll
        for (int nt = 0; nt < 4; nt++) {
            int col = nt * 16 + c;
            float bb = be3[col];
            float ss = 0.f, qq = 0.f;
#pragma unroll
            for (int rr = 0; rr < 4; rr++) {
                int e = blockb + tt * 64 + w * 16 + g * 4 + rr;
                float v = a3[tt][nt][rr] + bb;
                __builtin_nontemporal_store(v, &eout[(size_t)e * 64 + col]);
                ss += v; qq += v * v;
            }
            ss += __shfl_xor(ss, 16); ss += __shfl_xor(ss, 32);
            qq += __shfl_xor(qq, 16); qq += __shfl_xor(qq, 32);
            if (g == 0) { atomicAdd(&bs[col], ss); atomicAdd(&bs[64 + col], qq); }
        }
    __syncthreads();
    if (t < 128) pws[(size_t)t * (NE / 128) + blockIdx.x] = bs[t];
}

// ---------------- k4r: reduce per-block partials -> edge BN sums ----------------
__global__ __launch_bounds__(256) void k4r(const float* __restrict__ pws, float* __restrict__ sums) {
    int b = blockIdx.x;
    float s = 0.f;
    for (int i = threadIdx.x; i < NE / 128; i += 256) s += pws[(size_t)b * (NE / 128) + i];
#pragma unroll
    for (int m = 32; m >= 1; m >>= 1) s += __shfl_xor(s, m);
    __shared__ float acc4[4];
    int lane = threadIdx.x & 63, wid = threadIdx.x >> 6;
    if (lane == 0) acc4[wid] = s;
    __syncthreads();
    if (threadIdx.x == 0) sums[128 + b] = acc4[0] + acc4[1] + acc4[2] + acc4[3];
}

// ---------------- k5: edge_out = relu(BN(e3)) in-place; grid-stride, LDS col params, NT ----------------
__global__ __launch_bounds__(256) void k5(float* __restrict__ eo, const float* __restrict__ sums,
                                          const float* __restrict__ ge, const float* __restrict__ be) {
    __shared__ float sc[64], sh[64];
    if (threadIdx.x < 64) {
        int col = threadIdx.x;
        float m   = sums[128 + col] * (1.0f / 800000.0f);
        float var = sums[192 + col] * (1.0f / 800000.0f) - m * m;
        float inv = rsqrtf(var + 1e-5f) * ge[col];
        sc[col] = inv;
        sh[col] = be[col] - m * inv;
    }
    __syncthreads();
    const size_t total = (size_t)NE * 64 / 4;   // float4 count
    for (size_t i = (size_t)blockIdx.x * 256 + threadIdx.x; i < total; i += (size_t)gridDim.x * 256) {
        f32x4 v = __builtin_nontemporal_load(reinterpret_cast<const f32x4*>(eo) + i);
        int col0 = (int)((i * 4) & 63);
        f32x4 o;
#pragma unroll
        for (int j = 0; j < 4; j++) {
            float x = v[j] * sc[col0 + j] + sh[col0 + j];
            o[j] = x > 0.f ? x : 0.f;
        }
        __builtin_nontemporal_store(o, reinterpret_cast<f32x4*>(eo) + i);
    }
}

extern "C" void kernel_launch(void* const* d_in, const int* in_sizes, int n_in,
                              void* d_out, int out_size, void* d_ws, size_t ws_size,
                              hipStream_t stream) {
    const float* em   = (const float*)d_in[0];
    const int*   eidx = (const int*)d_in[1];
    const float* ef   = (const float*)d_in[2];
    const float* b_le = (const float*)d_in[4];
    const float* b1   = (const float*)d_in[6];
    const float* b2   = (const float*)d_in[8];
    const float* gx   = (const float*)d_in[9];
    const float* bx   = (const float*)d_in[10];
    const float* be1  = (const float*)d_in[12];
    const float* be2  = (const float*)d_in[14];
    const float* be3  = (const float*)d_in[16];
    const float* ge   = (const float*)d_in[17];
    const float* be   = (const float*)d_in[18];

    float* out = (float*)d_out;
    float* nodebuf = out;                          // 50000*64 f32 (aggr -> h2 -> x_em in place)
    float* eout = out + (size_t)NN * 64;           // 800000*64 f32 (e3 -> edge_out in place)

    // ws layout: sums 1KB | wfr 64KB | wsx 6.4MB | pws 3.2MB
    float*  sums = (float*)d_ws;
    __bf16* wfr  = (__bf16*)((char*)d_ws + 1024);
    __bf16* wsx  = (__bf16*)((char*)d_ws + 1024 + 65536);
    float*  pws  = (float*)((char*)d_ws + 1024 + 65536 + (size_t)NN * 64 * 2);

    hipMemsetAsync(nodebuf, 0, (size_t)NN * 64 * sizeof(float), stream);

    prep<<<16, 256, 0, stream>>>((const float*)d_in[3], (const float*)d_in[5], (const float*)d_in[7],
                                 (const float*)d_in[11], (const float*)d_in[13], (const float*)d_in[15],
                                 wfr, sums);
    k1<<<NE / 64, 256, 0, stream>>>(em, eidx, ef, wfr, b_le, nodebuf);
    k2<<<(NN + 63) / 64, 256, 0, stream>>>(em, nodebuf, wfr, b1, b2, sums);
    k3<<<(NN * 64) / 1024, 256, 0, stream>>>(nodebuf, sums, gx, bx, wsx);
    k4<<<NE / 128, 256, 0, stream>>>(eidx, ef, wsx, wfr, be1, be2, be3, eout, pws);
    k4r<<<128, 256, 0, stream>>>(pws, sums);
    k5<<<2048, 256, 0, stream>>>(eout, sums, ge, be);
}